// Round 1
// baseline (1483.882 us; speedup 1.0000x reference)
//
#include <hip/hip_runtime.h>
#include <math.h>
#include <stdint.h>

#define NCOL 32768
#define NROW 4
#define KSEL 1000
#define TPB  1024
#define EPT  32          // elements per thread: 1024*32 = 32768
#define NW   16          // waves per workgroup
#define FEPS 1.17549435e-38f   // np.finfo(np.float32).tiny

__device__ __forceinline__ float wred_sum(float v) {
#pragma unroll
  for (int m = 32; m; m >>= 1) v += __shfl_xor(v, m, 64);
  return v;
}
__device__ __forceinline__ float wred_max(float v) {
#pragma unroll
  for (int m = 32; m; m >>= 1) v = fmaxf(v, __shfl_xor(v, m, 64));
  return v;
}
__device__ __forceinline__ int wred_sum_i(int v) {
#pragma unroll
  for (int m = 32; m; m >>= 1) v += __shfl_xor(v, m, 64);
  return v;
}
// deterministic tree-sum of 16 floats (same order in every thread -> bit-identical W)
__device__ __forceinline__ float sum16(const float4* rp) {
  float4 a = rp[0], b = rp[1], c = rp[2], d = rp[3];
  float sa = (a.x + a.y) + (a.z + a.w);
  float sb = (b.x + b.y) + (b.z + b.w);
  float sc = (c.x + c.y) + (c.z + c.w);
  float sd = (d.x + d.y) + (d.z + d.w);
  return (sa + sb) + (sc + sd);
}

__global__ __launch_bounds__(TPB) void selhead_kernel(
    const float* __restrict__ logits,
    const float* __restrict__ gumbel,
    float* __restrict__ out)
{
  const int row  = blockIdx.x;
  const int tid  = threadIdx.x;
  const int lane = tid & 63;
  const int wv   = tid >> 6;
  const long rowoff = (long)row * NCOL;
  const float* lrow = logits + rowoff;
  const float* grow = gumbel + rowoff;
  const int base = tid * EPT;

  __shared__ __align__(16) float redA[NW];
  __shared__ __align__(16) float redB[NW];
  __shared__ __align__(16) float redW[2][NW];
  __shared__ int  redI[2][NW];
  __shared__ int  swtot[NW];

  float w[EPT];   // unnormalized softmax weights (shift-absorbed)
  float k[EPT];   // khot accumulator (temporarily holds logits in phase A)

  // ---------- Phase A: load, s0 = logits + gumbel, block maxes ----------
  float mxl = -INFINITY, mxs = -INFINITY;
#pragma unroll
  for (int j = 0; j < EPT; j += 4) {
    const float4 lv = *(const float4*)(lrow + base + j);
    const float4 gv = *(const float4*)(grow + base + j);
    k[j+0] = lv.x; k[j+1] = lv.y; k[j+2] = lv.z; k[j+3] = lv.w;
    w[j+0] = lv.x + gv.x; w[j+1] = lv.y + gv.y;
    w[j+2] = lv.z + gv.z; w[j+3] = lv.w + gv.w;
    mxl = fmaxf(mxl, fmaxf(fmaxf(lv.x, lv.y), fmaxf(lv.z, lv.w)));
    mxs = fmaxf(mxs, fmaxf(fmaxf(w[j+0], w[j+1]), fmaxf(w[j+2], w[j+3])));
  }
  {
    float wm_s = wred_max(mxs);
    float wm_l = wred_max(mxl);
    if (lane == 0) { redA[wv] = wm_s; redB[wv] = wm_l; }
  }
  __syncthreads();
  float M0 = -INFINITY, ML = -INFINITY;
#pragma unroll
  for (int i = 0; i < NW; ++i) {
    M0 = fmaxf(M0, redA[i]);
    ML = fmaxf(ML, redB[i]);
  }
  __syncthreads();   // protect redA before reuse

  // ---------- Phase B: SE = sum exp(logits - ML); w = exp(s0 - M0); k = 0 ----------
  float pse = 0.f;
  float pa0 = 0.f, pa1 = 0.f, pa2 = 0.f, pa3 = 0.f;
#pragma unroll
  for (int j = 0; j < EPT; j += 4) {
    pse += expf(k[j+0] - ML); pse += expf(k[j+1] - ML);
    pse += expf(k[j+2] - ML); pse += expf(k[j+3] - ML);
    w[j+0] = expf(w[j+0] - M0); w[j+1] = expf(w[j+1] - M0);
    w[j+2] = expf(w[j+2] - M0); w[j+3] = expf(w[j+3] - M0);
    pa0 += w[j+0]; pa1 += w[j+1]; pa2 += w[j+2]; pa3 += w[j+3];
    k[j+0] = 0.f; k[j+1] = 0.f; k[j+2] = 0.f; k[j+3] = 0.f;
  }
  float partial = (pa0 + pa1) + (pa2 + pa3);
  {
    float wse = wred_sum(pse);
    if (lane == 0) redA[wv] = wse;
  }
  __syncthreads();
  float SE = sum16((const float4*)redA);
  const float logZ = ML + logf(SE);   // log_softmax(x) = x - logZ

  // ---------- Phase C: K iterations of the telescoped update ----------
  for (int it = 0; it < KSEL; ++it) {
    float ws = wred_sum(partial);
    if (lane == 0) redW[it & 1][wv] = ws;
    __syncthreads();
    const float W = sum16((const float4*)redW[it & 1]);   // bit-identical in all lanes
    const float rcpW = 1.0f / W;
    float q0 = 0.f, q1 = 0.f, q2 = 0.f, q3 = 0.f;
#pragma unroll
    for (int j = 0; j < EPT; j += 4) {
      k[j+0] = fmaf(w[j+0], rcpW, k[j+0]);
      k[j+1] = fmaf(w[j+1], rcpW, k[j+1]);
      k[j+2] = fmaf(w[j+2], rcpW, k[j+2]);
      k[j+3] = fmaf(w[j+3], rcpW, k[j+3]);
      float t0 = fmaxf(fmaf(-w[j+0], rcpW, 1.0f), FEPS);
      float t1 = fmaxf(fmaf(-w[j+1], rcpW, 1.0f), FEPS);
      float t2 = fmaxf(fmaf(-w[j+2], rcpW, 1.0f), FEPS);
      float t3 = fmaxf(fmaf(-w[j+3], rcpW, 1.0f), FEPS);
      w[j+0] *= t0; w[j+1] *= t1; w[j+2] *= t2; w[j+3] *= t3;
      q0 += w[j+0]; q1 += w[j+1]; q2 += w[j+2]; q3 += w[j+3];
    }
    partial = (q0 + q1) + (q2 + q3);
  }

  // ---------- Phase D: top-KSEL threshold via 32-step radix binary search ----------
  // khot >= 0, so uint bit-pattern order == value order.
  uint32_t ku[EPT];
#pragma unroll
  for (int j = 0; j < EPT; ++j) ku[j] = __float_as_uint(k[j]);

  int step = 0;
  uint32_t T = 0;
  for (int bit = 31; bit >= 0; --bit, ++step) {
    const uint32_t cand = T | (1u << bit);
    int c = 0;
#pragma unroll
    for (int j = 0; j < EPT; ++j) c += (ku[j] >= cand) ? 1 : 0;
    int wc = wred_sum_i(c);
    if (lane == 0) redI[step & 1][wv] = wc;
    __syncthreads();
    int tot = 0;
#pragma unroll
    for (int i = 0; i < NW; ++i) tot += redI[step & 1][i];
    if (tot >= KSEL) T = cand;   // uniform decision (same tot in all threads)
  }
  // count strictly greater than T
  {
    int cg = 0;
#pragma unroll
    for (int j = 0; j < EPT; ++j) cg += (ku[j] > T) ? 1 : 0;
    int wcg = wred_sum_i(cg);
    if (lane == 0) redI[step & 1][wv] = wcg;
  }
  __syncthreads();
  int c_gt = 0;
#pragma unroll
  for (int i = 0; i < NW; ++i) c_gt += redI[step & 1][i];
  const int rneed = KSEL - c_gt;   // ties (== T) to take, lowest index first

  // exclusive prefix of tie-counts in index order (thread chunks are contiguous)
  int tcnt = 0;
#pragma unroll
  for (int j = 0; j < EPT; ++j) tcnt += (ku[j] == T) ? 1 : 0;
  int isc = tcnt;
#pragma unroll
  for (int d = 1; d < 64; d <<= 1) {
    int nb = __shfl_up(isc, d, 64);
    if (lane >= d) isc += nb;
  }
  if (lane == 63) swtot[wv] = isc;
  __syncthreads();
  int woff = 0;
#pragma unroll
  for (int i = 0; i < NW; ++i) if (i < wv) woff += swtot[i];
  int rk = woff + (isc - tcnt);   // global exclusive tie-rank at chunk start

  // ---------- Phase E: outputs ----------
  // out layout: values[4] | logprobs[4*32768] | actions[4*32768]
  float* outlp = out + NROW + rowoff;
  float* outac = out + NROW + (long)NROW * NCOL + rowoff;
  if (tid == 0) out[row] = 1.0f / (1.0f + expf(-ML));

  // actions: straight-through value (h - k) + k, computed in index order for ties
#pragma unroll
  for (int j = 0; j < EPT; ++j) {
    const uint32_t u = ku[j];
    const bool sel = (u > T) || ((u == T) && (rk < rneed));
    if (u == T) ++rk;
    w[j] = sel ? ((1.0f - k[j]) + k[j]) : 0.0f;
  }
#pragma unroll
  for (int j = 0; j < EPT; j += 4) {
    const float4 lv = *(const float4*)(lrow + base + j);
    float4 ac; ac.x = w[j+0]; ac.y = w[j+1]; ac.z = w[j+2]; ac.w = w[j+3];
    float4 lp;
    lp.x = (lv.x - logZ) * ac.x;
    lp.y = (lv.y - logZ) * ac.y;
    lp.z = (lv.z - logZ) * ac.z;
    lp.w = (lv.w - logZ) * ac.w;
    *(float4*)(outlp + base + j) = lp;
    *(float4*)(outac + base + j) = ac;
  }
}

extern "C" void kernel_launch(void* const* d_in, const int* in_sizes, int n_in,
                              void* d_out, int out_size, void* d_ws, size_t ws_size,
                              hipStream_t stream) {
  const float* logits = (const float*)d_in[0];
  const float* gumbel = (const float*)d_in[1];
  float* out = (float*)d_out;
  hipLaunchKernelGGL(selhead_kernel, dim3(NROW), dim3(TPB), 0, stream,
                     logits, gumbel, out);
}

// Round 2
// 1483.752 us; speedup vs baseline: 1.0001x; 1.0001x over previous
//
#include <hip/hip_runtime.h>
#include <math.h>
#include <stdint.h>

#define NCOL 32768
#define NROW 4
#define KSEL 1000
#define TPB  1024
#define EPT  32          // elements per thread: 1024*32 = 32768
#define NW   16          // waves per workgroup
#define FEPS 1.17549435e-38f   // np.finfo(np.float32).tiny

__device__ __forceinline__ float wred_sum(float v) {
#pragma unroll
  for (int m = 32; m; m >>= 1) v += __shfl_xor(v, m, 64);
  return v;
}
__device__ __forceinline__ float wred_max(float v) {
#pragma unroll
  for (int m = 32; m; m >>= 1) v = fmaxf(v, __shfl_xor(v, m, 64));
  return v;
}
__device__ __forceinline__ int wred_sum_i(int v) {
#pragma unroll
  for (int m = 32; m; m >>= 1) v += __shfl_xor(v, m, 64);
  return v;
}
// deterministic tree-sum of 16 floats (same order in every thread -> bit-identical W)
__device__ __forceinline__ float sum16(const float4* rp) {
  float4 a = rp[0], b = rp[1], c = rp[2], d = rp[3];
  float sa = (a.x + a.y) + (a.z + a.w);
  float sb = (b.x + b.y) + (b.z + b.w);
  float sc = (c.x + c.y) + (c.z + c.w);
  float sd = (d.x + d.y) + (d.z + d.w);
  return (sa + sb) + (sc + sd);
}

// __launch_bounds__(1024, 4): 4 waves/EU min = 16 waves/CU = exactly one
// 1024-thread block per CU. Raises VGPR cap 64 -> 128 so w[32]+k[32] stay
// in registers (64-VGPR default spilled them to scratch: R1 showed
// VGPR_Count=64 with >=64 live floats -> spill traffic in the hot loop).
__global__ __launch_bounds__(TPB, 4) void selhead_kernel(
    const float* __restrict__ logits,
    const float* __restrict__ gumbel,
    float* __restrict__ out)
{
  const int row  = blockIdx.x;
  const int tid  = threadIdx.x;
  const int lane = tid & 63;
  const int wv   = tid >> 6;
  const long rowoff = (long)row * NCOL;
  const float* lrow = logits + rowoff;
  const float* grow = gumbel + rowoff;
  const int base = tid * EPT;

  __shared__ __align__(16) float redA[NW];
  __shared__ __align__(16) float redB[NW];
  __shared__ __align__(16) float redW[2][NW];
  __shared__ int  redI[2][NW];
  __shared__ int  swtot[NW];

  float w[EPT];   // unnormalized softmax weights (shift-absorbed)
  float k[EPT];   // khot accumulator (temporarily holds logits in phase A)

  // ---------- Phase A: load, s0 = logits + gumbel, block maxes ----------
  float mxl = -INFINITY, mxs = -INFINITY;
#pragma unroll
  for (int j = 0; j < EPT; j += 4) {
    const float4 lv = *(const float4*)(lrow + base + j);
    const float4 gv = *(const float4*)(grow + base + j);
    k[j+0] = lv.x; k[j+1] = lv.y; k[j+2] = lv.z; k[j+3] = lv.w;
    w[j+0] = lv.x + gv.x; w[j+1] = lv.y + gv.y;
    w[j+2] = lv.z + gv.z; w[j+3] = lv.w + gv.w;
    mxl = fmaxf(mxl, fmaxf(fmaxf(lv.x, lv.y), fmaxf(lv.z, lv.w)));
    mxs = fmaxf(mxs, fmaxf(fmaxf(w[j+0], w[j+1]), fmaxf(w[j+2], w[j+3])));
  }
  {
    float wm_s = wred_max(mxs);
    float wm_l = wred_max(mxl);
    if (lane == 0) { redA[wv] = wm_s; redB[wv] = wm_l; }
  }
  __syncthreads();
  float M0 = -INFINITY, ML = -INFINITY;
#pragma unroll
  for (int i = 0; i < NW; ++i) {
    M0 = fmaxf(M0, redA[i]);
    ML = fmaxf(ML, redB[i]);
  }
  __syncthreads();   // protect redA before reuse

  // ---------- Phase B: SE = sum exp(logits - ML); w = exp(s0 - M0); k = 0 ----------
  float pse = 0.f;
  float pa0 = 0.f, pa1 = 0.f, pa2 = 0.f, pa3 = 0.f;
#pragma unroll
  for (int j = 0; j < EPT; j += 4) {
    pse += expf(k[j+0] - ML); pse += expf(k[j+1] - ML);
    pse += expf(k[j+2] - ML); pse += expf(k[j+3] - ML);
    w[j+0] = expf(w[j+0] - M0); w[j+1] = expf(w[j+1] - M0);
    w[j+2] = expf(w[j+2] - M0); w[j+3] = expf(w[j+3] - M0);
    pa0 += w[j+0]; pa1 += w[j+1]; pa2 += w[j+2]; pa3 += w[j+3];
    k[j+0] = 0.f; k[j+1] = 0.f; k[j+2] = 0.f; k[j+3] = 0.f;
  }
  float partial = (pa0 + pa1) + (pa2 + pa3);
  {
    float wse = wred_sum(pse);
    if (lane == 0) redA[wv] = wse;
  }
  __syncthreads();
  float SE = sum16((const float4*)redA);
  const float logZ = ML + logf(SE);   // log_softmax(x) = x - logZ

  // ---------- Phase C: K iterations of the telescoped update ----------
  for (int it = 0; it < KSEL; ++it) {
    float ws = wred_sum(partial);
    if (lane == 0) redW[it & 1][wv] = ws;
    __syncthreads();
    const float W = sum16((const float4*)redW[it & 1]);   // bit-identical in all lanes
    const float rcpW = 1.0f / W;
    float q0 = 0.f, q1 = 0.f, q2 = 0.f, q3 = 0.f;
#pragma unroll
    for (int j = 0; j < EPT; j += 4) {
      k[j+0] = fmaf(w[j+0], rcpW, k[j+0]);
      k[j+1] = fmaf(w[j+1], rcpW, k[j+1]);
      k[j+2] = fmaf(w[j+2], rcpW, k[j+2]);
      k[j+3] = fmaf(w[j+3], rcpW, k[j+3]);
      float t0 = fmaxf(fmaf(-w[j+0], rcpW, 1.0f), FEPS);
      float t1 = fmaxf(fmaf(-w[j+1], rcpW, 1.0f), FEPS);
      float t2 = fmaxf(fmaf(-w[j+2], rcpW, 1.0f), FEPS);
      float t3 = fmaxf(fmaf(-w[j+3], rcpW, 1.0f), FEPS);
      w[j+0] *= t0; w[j+1] *= t1; w[j+2] *= t2; w[j+3] *= t3;
      q0 += w[j+0]; q1 += w[j+1]; q2 += w[j+2]; q3 += w[j+3];
    }
    partial = (q0 + q1) + (q2 + q3);
  }

  // ---------- Phase D: top-KSEL threshold via 32-step radix binary search ----------
  // khot >= 0, so uint bit-pattern order == value order.
  uint32_t ku[EPT];
#pragma unroll
  for (int j = 0; j < EPT; ++j) ku[j] = __float_as_uint(k[j]);

  int step = 0;
  uint32_t T = 0;
  for (int bit = 31; bit >= 0; --bit, ++step) {
    const uint32_t cand = T | (1u << bit);
    int c = 0;
#pragma unroll
    for (int j = 0; j < EPT; ++j) c += (ku[j] >= cand) ? 1 : 0;
    int wc = wred_sum_i(c);
    if (lane == 0) redI[step & 1][wv] = wc;
    __syncthreads();
    int tot = 0;
#pragma unroll
    for (int i = 0; i < NW; ++i) tot += redI[step & 1][i];
    if (tot >= KSEL) T = cand;   // uniform decision (same tot in all threads)
  }
  // count strictly greater than T
  {
    int cg = 0;
#pragma unroll
    for (int j = 0; j < EPT; ++j) cg += (ku[j] > T) ? 1 : 0;
    int wcg = wred_sum_i(cg);
    if (lane == 0) redI[step & 1][wv] = wcg;
  }
  __syncthreads();
  int c_gt = 0;
#pragma unroll
  for (int i = 0; i < NW; ++i) c_gt += redI[step & 1][i];
  const int rneed = KSEL - c_gt;   // ties (== T) to take, lowest index first

  // exclusive prefix of tie-counts in index order (thread chunks are contiguous)
  int tcnt = 0;
#pragma unroll
  for (int j = 0; j < EPT; ++j) tcnt += (ku[j] == T) ? 1 : 0;
  int isc = tcnt;
#pragma unroll
  for (int d = 1; d < 64; d <<= 1) {
    int nb = __shfl_up(isc, d, 64);
    if (lane >= d) isc += nb;
  }
  if (lane == 63) swtot[wv] = isc;
  __syncthreads();
  int woff = 0;
#pragma unroll
  for (int i = 0; i < NW; ++i) if (i < wv) woff += swtot[i];
  int rk = woff + (isc - tcnt);   // global exclusive tie-rank at chunk start

  // ---------- Phase E: outputs ----------
  // out layout: values[4] | logprobs[4*32768] | actions[4*32768]
  float* outlp = out + NROW + rowoff;
  float* outac = out + NROW + (long)NROW * NCOL + rowoff;
  if (tid == 0) out[row] = 1.0f / (1.0f + expf(-ML));

  // actions: straight-through value (h - k) + k, computed in index order for ties
#pragma unroll
  for (int j = 0; j < EPT; ++j) {
    const uint32_t u = ku[j];
    const bool sel = (u > T) || ((u == T) && (rk < rneed));
    if (u == T) ++rk;
    w[j] = sel ? ((1.0f - k[j]) + k[j]) : 0.0f;
  }
#pragma unroll
  for (int j = 0; j < EPT; j += 4) {
    const float4 lv = *(const float4*)(lrow + base + j);
    float4 ac; ac.x = w[j+0]; ac.y = w[j+1]; ac.z = w[j+2]; ac.w = w[j+3];
    float4 lp;
    lp.x = (lv.x - logZ) * ac.x;
    lp.y = (lv.y - logZ) * ac.y;
    lp.z = (lv.z - logZ) * ac.z;
    lp.w = (lv.w - logZ) * ac.w;
    *(float4*)(outlp + base + j) = lp;
    *(float4*)(outac + base + j) = ac;
  }
}

extern "C" void kernel_launch(void* const* d_in, const int* in_sizes, int n_in,
                              void* d_out, int out_size, void* d_ws, size_t ws_size,
                              hipStream_t stream) {
  const float* logits = (const float*)d_in[0];
  const float* gumbel = (const float*)d_in[1];
  float* out = (float*)d_out;
  hipLaunchKernelGGL(selhead_kernel, dim3(NROW), dim3(TPB), 0, stream,
                     logits, gumbel, out);
}

// Round 3
// 1363.249 us; speedup vs baseline: 1.0885x; 1.0884x over previous
//
#include <hip/hip_runtime.h>
#include <math.h>
#include <stdint.h>

#define NCOL 32768
#define NROW 4
#define KSEL 1000
#define NRND (KSEL / 2)   // two exact softmax steps per reduction round
#define TPB  1024
#define EPT  32           // elements per thread: 1024*32 = 32768
#define NW   16           // waves per workgroup
#define FEPS 1.17549435e-38f

// ---- DPP 64-lane sum (rocPRIM pattern): 6 VALU-speed ops, total in lane 63 ----
template<int ctrl, int rmask, int bmask>
__device__ __forceinline__ float dppmv(float x) {
  return __int_as_float(__builtin_amdgcn_update_dpp(
      0, __float_as_int(x), ctrl, rmask, bmask, false));
}
__device__ __forceinline__ float dpp_wave_sum(float v) {
  v += dppmv<0x111, 0xf, 0xf>(v);   // row_shr:1
  v += dppmv<0x112, 0xf, 0xf>(v);   // row_shr:2
  v += dppmv<0x114, 0xf, 0xe>(v);   // row_shr:4  (bank0 masked)
  v += dppmv<0x118, 0xf, 0xc>(v);   // row_shr:8  (banks0,1 masked)
  v += dppmv<0x142, 0xa, 0xf>(v);   // row_bcast:15 -> rows 1,3
  v += dppmv<0x143, 0xc, 0xf>(v);   // row_bcast:31 -> rows 2,3
  return v;                          // lane 63 holds the wave total
}

__device__ __forceinline__ float wred_sum(float v) {
#pragma unroll
  for (int m = 32; m; m >>= 1) v += __shfl_xor(v, m, 64);
  return v;
}
__device__ __forceinline__ float wred_max(float v) {
#pragma unroll
  for (int m = 32; m; m >>= 1) v = fmaxf(v, __shfl_xor(v, m, 64));
  return v;
}
__device__ __forceinline__ int wred_sum_i(int v) {
#pragma unroll
  for (int m = 32; m; m >>= 1) v += __shfl_xor(v, m, 64);
  return v;
}
// deterministic tree-sum of 16 floats (same order in every thread -> bit-identical)
__device__ __forceinline__ float sum16(const float4* rp) {
  float4 a = rp[0], b = rp[1], c = rp[2], d = rp[3];
  float sa = (a.x + a.y) + (a.z + a.w);
  float sb = (b.x + b.y) + (b.z + b.w);
  float sc = (c.x + c.y) + (c.z + c.w);
  float sd = (d.x + d.y) + (d.z + d.w);
  return (sa + sb) + (sc + sd);
}

__global__ __launch_bounds__(TPB, 4) void selhead_kernel(
    const float* __restrict__ logits,
    const float* __restrict__ gumbel,
    float* __restrict__ out)
{
  const int row  = blockIdx.x;
  const int tid  = threadIdx.x;
  const int lane = tid & 63;
  const int wv   = tid >> 6;
  const long rowoff = (long)row * NCOL;
  const float* lrow = logits + rowoff;
  const float* grow = gumbel + rowoff;
  const int base = tid * EPT;

  __shared__ __align__(16) float redA[NW];
  __shared__ __align__(16) float redB[NW];
  __shared__ __align__(16) float redW1[2][NW];
  __shared__ __align__(16) float redW2[2][NW];
  __shared__ int  redI[2][NW];
  __shared__ int  swtot[NW];

  float w[EPT];   // unnormalized softmax weights (shift-absorbed)
  float k[EPT];   // khot accumulator (temporarily holds logits in phase A)

  // ---------- Phase A: load, s0 = logits + gumbel, block maxes ----------
  float mxl = -INFINITY, mxs = -INFINITY;
#pragma unroll
  for (int j = 0; j < EPT; j += 4) {
    const float4 lv = *(const float4*)(lrow + base + j);
    const float4 gv = *(const float4*)(grow + base + j);
    k[j+0] = lv.x; k[j+1] = lv.y; k[j+2] = lv.z; k[j+3] = lv.w;
    w[j+0] = lv.x + gv.x; w[j+1] = lv.y + gv.y;
    w[j+2] = lv.z + gv.z; w[j+3] = lv.w + gv.w;
    mxl = fmaxf(mxl, fmaxf(fmaxf(lv.x, lv.y), fmaxf(lv.z, lv.w)));
    mxs = fmaxf(mxs, fmaxf(fmaxf(w[j+0], w[j+1]), fmaxf(w[j+2], w[j+3])));
  }
  {
    float wm_s = wred_max(mxs);
    float wm_l = wred_max(mxl);
    if (lane == 0) { redA[wv] = wm_s; redB[wv] = wm_l; }
  }
  __syncthreads();
  float M0 = -INFINITY, ML = -INFINITY;
#pragma unroll
  for (int i = 0; i < NW; ++i) {
    M0 = fmaxf(M0, redA[i]);
    ML = fmaxf(ML, redB[i]);
  }
  __syncthreads();   // protect redA before reuse

  // ---------- Phase B: SE = sum exp(logits - ML); w = exp(s0 - M0); k = 0 ----------
  float pse = 0.f;
  float pa0 = 0.f, pa1 = 0.f;      // S1 partials
  float pb0 = 0.f, pb1 = 0.f;      // S2 partials
#pragma unroll
  for (int j = 0; j < EPT; j += 2) {
    pse += expf(k[j+0] - ML); pse += expf(k[j+1] - ML);
    w[j+0] = expf(w[j+0] - M0); w[j+1] = expf(w[j+1] - M0);
    pa0 += w[j+0];                 pa1 += w[j+1];
    pb0 = fmaf(w[j+0], w[j+0], pb0);
    pb1 = fmaf(w[j+1], w[j+1], pb1);
    k[j+0] = 0.f; k[j+1] = 0.f;
  }
  float s1 = pa0 + pa1;
  float s2 = pb0 + pb1;
  {
    float wse = wred_sum(pse);
    if (lane == 0) redA[wv] = wse;
  }
  __syncthreads();
  float SE = sum16((const float4*)redA);
  const float logZ = ML + logf(SE);   // log_softmax(x) = x - logZ

  // ---------- Phase C: NRND rounds, 2 exact softmax steps per round ----------
  // W_{t+1} = W_t - S2_t/W_t  (exact: sum of w*(1-w/W) over all elements)
  for (int rd = 0; rd < NRND; ++rd) {
    float r1 = dpp_wave_sum(s1);
    float r2 = dpp_wave_sum(s2);
    if (lane == 63) { redW1[rd & 1][wv] = r1; redW2[rd & 1][wv] = r2; }
    __syncthreads();
    const float S1 = sum16((const float4*)redW1[rd & 1]);  // bit-identical in all lanes
    const float S2 = sum16((const float4*)redW2[rd & 1]);
    const float WB = S1 - S2 / S1;        // sum after step A, exact
    const float rA = 1.0f / S1;
    const float rB = 1.0f / WB;
    float a0 = 0.f, a1 = 0.f;   // next S1 partials
    float b0 = 0.f, b1 = 0.f;   // next S2 partials
#pragma unroll
    for (int j = 0; j < EPT; j += 2) {
      // step A
      float pA0 = w[j+0] * rA,  pA1 = w[j+1] * rA;
      k[j+0] += pA0;            k[j+1] += pA1;
      float u0 = fmaxf(fmaf(-pA0, w[j+0], w[j+0]), 0.f);
      float u1 = fmaxf(fmaf(-pA1, w[j+1], w[j+1]), 0.f);
      // step B
      float pB0 = u0 * rB,      pB1 = u1 * rB;
      k[j+0] += pB0;            k[j+1] += pB1;
      u0 = fmaxf(fmaf(-pB0, u0, u0), 0.f);
      u1 = fmaxf(fmaf(-pB1, u1, u1), 0.f);
      w[j+0] = u0;              w[j+1] = u1;
      a0 += u0;                 a1 += u1;
      b0 = fmaf(u0, u0, b0);    b1 = fmaf(u1, u1, b1);
    }
    s1 = a0 + a1;
    s2 = b0 + b1;
  }

  // ---------- Phase D: top-KSEL threshold via 32-step radix binary search ----------
  // khot >= 0, so uint bit-pattern order == value order.
  uint32_t ku[EPT];
#pragma unroll
  for (int j = 0; j < EPT; ++j) ku[j] = __float_as_uint(k[j]);

  int step = 0;
  uint32_t T = 0;
  for (int bit = 31; bit >= 0; --bit, ++step) {
    const uint32_t cand = T | (1u << bit);
    int c = 0;
#pragma unroll
    for (int j = 0; j < EPT; ++j) c += (ku[j] >= cand) ? 1 : 0;
    int wc = wred_sum_i(c);
    if (lane == 0) redI[step & 1][wv] = wc;
    __syncthreads();
    int tot = 0;
#pragma unroll
    for (int i = 0; i < NW; ++i) tot += redI[step & 1][i];
    if (tot >= KSEL) T = cand;   // uniform decision (same tot in all threads)
  }
  // count strictly greater than T
  {
    int cg = 0;
#pragma unroll
    for (int j = 0; j < EPT; ++j) cg += (ku[j] > T) ? 1 : 0;
    int wcg = wred_sum_i(cg);
    if (lane == 0) redI[step & 1][wv] = wcg;
  }
  __syncthreads();
  int c_gt = 0;
#pragma unroll
  for (int i = 0; i < NW; ++i) c_gt += redI[step & 1][i];
  const int rneed = KSEL - c_gt;   // ties (== T) to take, lowest index first

  // exclusive prefix of tie-counts in index order (thread chunks are contiguous)
  int tcnt = 0;
#pragma unroll
  for (int j = 0; j < EPT; ++j) tcnt += (ku[j] == T) ? 1 : 0;
  int isc = tcnt;
#pragma unroll
  for (int d = 1; d < 64; d <<= 1) {
    int nb = __shfl_up(isc, d, 64);
    if (lane >= d) isc += nb;
  }
  if (lane == 63) swtot[wv] = isc;
  __syncthreads();
  int woff = 0;
#pragma unroll
  for (int i = 0; i < NW; ++i) if (i < wv) woff += swtot[i];
  int rk = woff + (isc - tcnt);   // global exclusive tie-rank at chunk start

  // ---------- Phase E: outputs ----------
  // out layout: values[4] | logprobs[4*32768] | actions[4*32768]
  float* outlp = out + NROW + rowoff;
  float* outac = out + NROW + (long)NROW * NCOL + rowoff;
  if (tid == 0) out[row] = 1.0f / (1.0f + expf(-ML));

  // actions: straight-through value (h - k) + k, computed in index order for ties
#pragma unroll
  for (int j = 0; j < EPT; ++j) {
    const uint32_t u = ku[j];
    const bool sel = (u > T) || ((u == T) && (rk < rneed));
    if (u == T) ++rk;
    w[j] = sel ? ((1.0f - k[j]) + k[j]) : 0.0f;
  }
#pragma unroll
  for (int j = 0; j < EPT; j += 4) {
    const float4 lv = *(const float4*)(lrow + base + j);
    float4 ac; ac.x = w[j+0]; ac.y = w[j+1]; ac.z = w[j+2]; ac.w = w[j+3];
    float4 lp;
    lp.x = (lv.x - logZ) * ac.x;
    lp.y = (lv.y - logZ) * ac.y;
    lp.z = (lv.z - logZ) * ac.z;
    lp.w = (lv.w - logZ) * ac.w;
    *(float4*)(outlp + base + j) = lp;
    *(float4*)(outac + base + j) = ac;
  }
}

extern "C" void kernel_launch(void* const* d_in, const int* in_sizes, int n_in,
                              void* d_out, int out_size, void* d_ws, size_t ws_size,
                              hipStream_t stream) {
  const float* logits = (const float*)d_in[0];
  const float* gumbel = (const float*)d_in[1];
  float* out = (float*)d_out;
  hipLaunchKernelGGL(selhead_kernel, dim3(NROW), dim3(TPB), 0, stream,
                     logits, gumbel, out);
}